// Round 14
// baseline (225.483 us; speedup 1.0000x reference)
//
#include <hip/hip_runtime.h>
#include <hip/hip_bf16.h>
#include <math.h>

#define DD 1024
#define LWW 16
#define NNODES 255
#define NLEAF 256
#define BB 2
#define SS 1024
#define NTOK (BB*SS)
#define PLANE ((size_t)NTOK * DD)   // 2M elements per bf16 plane
#define MS ((size_t)1024 * 1024)    // per-batch matrix stride
#define MAXCHUNK 512                // per-tree chunk-descriptor slots
#define CH 8                        // tokens per chunk

typedef short bf16x8 __attribute__((ext_vector_type(8)));
typedef float f32x4 __attribute__((ext_vector_type(4)));

#define GLOBAL_AS __attribute__((address_space(1)))
#define LDS_AS __attribute__((address_space(3)))

__device__ __forceinline__ void gld_lds16(const void* g, void* l) {
  __builtin_amdgcn_global_load_lds((const GLOBAL_AS unsigned int*)g,
                                   (LDS_AS unsigned int*)l, 16, 0, 0);
}

__device__ __forceinline__ unsigned short f2bf(float f) {
  union { float f; unsigned int u; } v; v.f = f;
  unsigned int u = v.u;
  unsigned int lsb = (u >> 16) & 1u;
  u += 0x7fffu + lsb;
  return (unsigned short)(u >> 16);
}
__device__ __forceinline__ float bf2f(unsigned short h) {
  union { unsigned int u; float f; } v; v.u = ((unsigned int)h) << 16;
  return v.f;
}
// split f32 into 3 bf16 limbs (exact to ~2^-24 relative)
__device__ __forceinline__ void split3(float a, unsigned short& h0,
                                       unsigned short& h1, unsigned short& h2) {
  h0 = f2bf(a);
  float r = a - bf2f(h0);
  h1 = f2bf(r);
  float r2 = r - bf2f(h1);
  h2 = f2bf(r2);
}

// ---------------- fused norm + qkv routing ----------------
__global__ __launch_bounds__(256) void norm_route_kernel(
    const float* __restrict__ x, float* __restrict__ xn,
    const float* nw0, const float* nb0,
    const float* nw1, const float* nb1,
    const float* nw2, const float* nb2,
    int* __restrict__ leaf_arr, int* __restrict__ hist) {
  int tok = blockIdx.x, tid = threadIdx.x;
  int wid = tid >> 6, lane = tid & 63;
  __shared__ double rs[4], rs2[4];
  __shared__ float stats[2];
  __shared__ float xs[1024];
  const float4 v = ((const float4*)(x + (size_t)tok * DD))[tid];
  double s = (double)v.x + (double)v.y + (double)v.z + (double)v.w;
  double s2 = (double)v.x * v.x + (double)v.y * v.y + (double)v.z * v.z + (double)v.w * v.w;
  for (int o = 32; o; o >>= 1) { s += __shfl_down(s, o); s2 += __shfl_down(s2, o); }
  if (lane == 0) { rs[wid] = s; rs2[wid] = s2; }
  __syncthreads();
  if (tid == 0) {
    double ts = rs[0] + rs[1] + rs[2] + rs[3];
    double ts2 = rs2[0] + rs2[1] + rs2[2] + rs2[3];
    double mu = ts / DD;
    double var = (ts2 - DD * mu * mu) / (DD - 1);
    if (var < 0) var = 0;
    double sd = sqrt(var);
    stats[0] = (float)mu;
    stats[1] = (float)(1.0 / sqrt(sd + 1e-5));
  }
  __syncthreads();
  float mu = stats[0], inv = stats[1];
  float4 o;
  o.x = (v.x - mu) * inv; o.y = (v.y - mu) * inv;
  o.z = (v.z - mu) * inv; o.w = (v.w - mu) * inv;
  ((float4*)(xn + (size_t)tok * DD))[tid] = o;
  *(float4*)&xs[tid * 4] = o;
  __syncthreads();

  if (wid < 3) {
    const float* nws[3] = {nw0, nw1, nw2};
    const float* nbs[3] = {nb0, nb1, nb2};
    const float* nw = nws[wid];
    const float* nb = nbs[wid];
    f32x4 xq[4];
#pragma unroll
    for (int j = 0; j < 4; ++j) xq[j] = *(const f32x4*)&xs[(lane + 64 * j) * 4];
    int node = 0;
#pragma unroll 1
    for (int step = 0; step < 8; ++step) {
      const f32x4* wb = (const f32x4*)(nw + (size_t)node * DD);
      double p = 0.0;
#pragma unroll
      for (int j = 0; j < 4; ++j) {
        f32x4 w = wb[lane + 64 * j];
        p += (double)xq[j][0] * w[0] + (double)xq[j][1] * w[1] +
             (double)xq[j][2] * w[2] + (double)xq[j][3] * w[3];
      }
#pragma unroll
      for (int o2 = 1; o2 < 64; o2 <<= 1) p += __shfl_xor(p, o2);
      double logit = p + (double)nb[node];
      node = 2 * node + 1 + (logit > 0.0 ? 1 : 0);
    }
    if (lane == 0) {
      int leaf = node - NNODES;
      leaf_arr[(size_t)wid * NTOK + tok] = leaf;
      atomicAdd(&hist[wid * NLEAF + leaf], 1);
    }
  }
}

// ---------------- routing (standalone, used for f tree on y) ----------------
__global__ __launch_bounds__(256) void route_kernel(
    const float* __restrict__ xin,
    const float* nw0, const float* nb0,
    const float* nw1, const float* nb1,
    const float* nw2, const float* nb2,
    int* __restrict__ leaf_arr, int* __restrict__ hist, int ntree) {
  int tid = threadIdx.x, lane = tid & 63, wid = tid >> 6;
  int gw = blockIdx.x * 4 + wid;
  int tok = gw / ntree, tr = gw - tok * ntree;
  if (tok >= NTOK) return;
  const float* nws[3] = {nw0, nw1, nw2};
  const float* nbs[3] = {nb0, nb1, nb2};
  const float* nw = nws[tr];
  const float* nb = nbs[tr];
  f32x4 xq[4];
  const f32x4* xb = (const f32x4*)(xin + (size_t)tok * DD);
#pragma unroll
  for (int j = 0; j < 4; ++j) xq[j] = xb[lane + 64 * j];
  int node = 0;
#pragma unroll 1
  for (int step = 0; step < 8; ++step) {
    const f32x4* wb = (const f32x4*)(nw + (size_t)node * DD);
    double p = 0.0;
#pragma unroll
    for (int j = 0; j < 4; ++j) {
      f32x4 w = wb[lane + 64 * j];
      p += (double)xq[j][0] * w[0] + (double)xq[j][1] * w[1] +
           (double)xq[j][2] * w[2] + (double)xq[j][3] * w[3];
    }
#pragma unroll
    for (int o = 1; o < 64; o <<= 1) p += __shfl_xor(p, o);
    double logit = p + (double)nb[node];
    node = 2 * node + 1 + (logit > 0.0 ? 1 : 0);
  }
  if (lane == 0) {
    int leaf = node - NNODES;
    leaf_arr[(size_t)tr * NTOK + tok] = leaf;
    atomicAdd(&hist[tr * NLEAF + leaf], 1);
  }
}

// ---------------- fused scan + scatter + desc padding (1 block) ----------------
__global__ __launch_bounds__(256) void scan_scatter_kernel(
    const int* __restrict__ hist, const int* __restrict__ leaf_arr,
    int* __restrict__ list, int4* __restrict__ desc,
    int ntree, int tree0) {
  __shared__ int buf[256];
  __shared__ int cur[256];
  __shared__ int dcnt;
  int tid = threadIdx.x;
  for (int tr = 0; tr < ntree; ++tr) {
    int slot = tree0 + tr;
    int v = hist[slot * NLEAF + tid];
    buf[tid] = v;
    if (tid == 0) dcnt = 0;
    __syncthreads();
    int run = v;
    for (int off = 1; off < 256; off <<= 1) {
      int add = (tid >= off) ? buf[tid - off] : 0;
      __syncthreads();
      run += add;
      buf[tid] = run;
      __syncthreads();
    }
    cur[tid] = run - v;
    if (v > 0) {
      int k = (v + CH - 1) / CH;
      int base = atomicAdd(&dcnt, k);
      int lo = run - v;
      for (int j = 0; j < k; ++j) {
        int s = lo + j * CH;
        int e = min(run, s + CH);
        desc[slot * MAXCHUNK + base + j] = make_int4(tid, s, e, 0);
      }
    }
    __syncthreads();
    for (int i = dcnt + tid; i < MAXCHUNK; i += 256)
      desc[slot * MAXCHUNK + i] = make_int4(-1, 0, 0, 0);
    for (int base = 0; base < NTOK; base += 256) {
      int tok = base + tid;
      int leaf = leaf_arr[(size_t)slot * NTOK + tok];
      int pos = atomicAdd(&cur[leaf], 1);
      list[(size_t)slot * NTOK + pos] = tok;
    }
    __syncthreads();
  }
}

// ---------------- leaf MLP v5 (unchanged) ----------------
struct LeafW {
  const float* w1[3]; const float* b1[3]; const float* w2[3]; const float* b2[3];
  unsigned short* outs[3];   // split-plane bases, or null
  float* out_res;            // residual f32 output (used when outs[ty]==null)
};

__global__ __launch_bounds__(256) void leafmlp_kernel(
    const float* __restrict__ xin,
    const int* __restrict__ list, const int4* __restrict__ desc,
    LeafW W, int tree0, int act) {
  int ty = blockIdx.y;
  int slot = tree0 + ty;
  int4 dsc = desc[slot * MAXCHUNK + blockIdx.x];
  int leaf = dsc.x;
  if (leaf < 0) return;
  int lo = dsc.y, hi = dsc.z;
  const int* L = list + (size_t)slot * NTOK;
  const float* W1 = W.w1[ty] + (size_t)leaf * DD * LWW;
  const float* B1 = W.b1[ty] + (size_t)leaf * LWW;
  const float* W2 = W.w2[ty] + (size_t)leaf * LWW * DD;
  const float* B2 = W.b2[ty] + (size_t)leaf * DD;
  unsigned short* osp = W.outs[ty];
  int tid = threadIdx.x;
  int lane = tid & 63, wid = tid >> 6;

  __shared__ float xsl[CH][1024];
  __shared__ float hpart[4][CH][20];
  __shared__ float hs[CH][16];

  float b1c = B1[tid & 15];

  int r = tid >> 2;
  const float* W1p = W1 + (size_t)r * 16 + (tid & 3) * 4;
  f32x4 wreg[16];
#pragma unroll
  for (int p = 0; p < 16; ++p) wreg[p] = *(const f32x4*)(W1p + (size_t)p * 1024);

  int toks[CH];
#pragma unroll
  for (int t = 0; t < CH; ++t) {
    int idx = lo + t;
    toks[t] = (idx < hi) ? L[idx] : -1;
    if (toks[t] >= 0) {
      float4 v = ((const float4*)(xin + (size_t)toks[t] * DD))[tid];
      *(float4*)&xsl[t][tid * 4] = v;
    } else {
      float4 z = {0.f, 0.f, 0.f, 0.f};
      *(float4*)&xsl[t][tid * 4] = z;
    }
  }
  __syncthreads();

  f32x4 part4[CH];
#pragma unroll
  for (int t = 0; t < CH; ++t) part4[t] = (f32x4){0.f, 0.f, 0.f, 0.f};
#pragma unroll
  for (int p = 0; p < 16; ++p) {
#pragma unroll
    for (int t = 0; t < CH; ++t) {
      float xv = xsl[t][p * 64 + r];
      part4[t] += xv * wreg[p];
    }
  }

  const float* W2p = W2 + tid * 4;
  f32x4 w2a[8];
#pragma unroll
  for (int l = 0; l < 8; ++l) w2a[l] = *(const f32x4*)(W2p + (size_t)l * 1024);
  f32x4 b2v = *(const f32x4*)(B2 + tid * 4);

#pragma unroll
  for (int t = 0; t < CH; ++t) {
    f32x4 v = part4[t];
#pragma unroll
    for (int o = 4; o < 64; o <<= 1) {
      v[0] += __shfl_xor(v[0], o);
      v[1] += __shfl_xor(v[1], o);
      v[2] += __shfl_xor(v[2], o);
      v[3] += __shfl_xor(v[3], o);
    }
    if (lane < 4) *(f32x4*)&hpart[wid][t][lane * 4] = v;
  }
  __syncthreads();

  if (tid < 16 * CH) {
    int t = tid >> 4, c = tid & 15;
    float h = b1c + hpart[0][t][c] + hpart[1][t][c] + hpart[2][t][c] + hpart[3][t][c];
    if (act == 0) h = fmaxf(h, 0.f);
    else h = 0.5f * h * (1.f + erff(h * 0.70710678118654752f));
    hs[t][c] = h;
  }
  __syncthreads();

  f32x4 w2b[8];
#pragma unroll
  for (int l = 0; l < 8; ++l) w2b[l] = *(const f32x4*)(W2p + (size_t)(8 + l) * 1024);
  f32x4 acc[CH];
#pragma unroll
  for (int t = 0; t < CH; ++t) acc[t] = b2v;
#pragma unroll
  for (int l = 0; l < 8; ++l) {
#pragma unroll
    for (int t = 0; t < CH; ++t) acc[t] += w2a[l] * hs[t][l];
  }
#pragma unroll
  for (int l = 0; l < 8; ++l) {
#pragma unroll
    for (int t = 0; t < CH; ++t) acc[t] += w2b[l] * hs[t][8 + l];
  }

#pragma unroll
  for (int t = 0; t < CH; ++t) {
    if (toks[t] < 0) break;
    size_t off = (size_t)toks[t] * DD + tid * 4;
    if (osp) {
      ushort4 o0, o1, o2;
      split3(acc[t][0], o0.x, o1.x, o2.x);
      split3(acc[t][1], o0.y, o1.y, o2.y);
      split3(acc[t][2], o0.z, o1.z, o2.z);
      split3(acc[t][3], o0.w, o1.w, o2.w);
      *(ushort4*)(osp + off) = o0;
      *(ushort4*)(osp + PLANE + off) = o1;
      *(ushort4*)(osp + 2 * PLANE + off) = o2;
    } else {
      float4 xr = *(const float4*)&xsl[t][tid * 4];
      float4 o;
      o.x = xr.x + acc[t][0];
      o.y = xr.y + acc[t][1];
      o.z = xr.z + acc[t][2];
      o.w = xr.w + acc[t][3];
      *(float4*)(W.out_res + off) = o;
    }
  }
}

// ---------------- transpose one bf16 plane-set: v (B,S,D) -> vt (B,D,S) ----------------
__global__ __launch_bounds__(256) void transpose_v(const unsigned short* __restrict__ v,
                                                   unsigned short* __restrict__ vt) {
  __shared__ unsigned short t[32][34];
  int b = blockIdx.z & 1, p = blockIdx.z >> 1;
  int s0 = blockIdx.x * 32, d0 = blockIdx.y * 32;
  int tx = threadIdx.x, ty = threadIdx.y;  // 32 x 8
  const unsigned short* vb = v + p * PLANE + (size_t)b * SS * DD;
  unsigned short* vtb = vt + p * PLANE + (size_t)b * DD * SS;
#pragma unroll
  for (int k = 0; k < 4; ++k) {
    int r = ty + 8 * k;
    t[r][tx] = vb[(size_t)(s0 + r) * DD + d0 + tx];
  }
  __syncthreads();
#pragma unroll
  for (int k = 0; k < 4; ++k) {
    int r = ty + 8 * k;
    vtb[(size_t)(d0 + r) * SS + s0 + tx] = t[tx][r];
  }
}

// ---------------- NT GEMM, 3-limb split bf16, 128x128 tile, XOR-swizzled LDS ----
// 8 waves (512 thr). Wave (wm=wid>>1, wn=wid&1) owns a 32x64 output strip.
// Traffic: input panels re-read 8x (vs 16x at 64-tile) -> 192 MB/dispatch.
// Per-output accumulation order identical to the 64-tile version -> bit-exact.
#define BKK 64
__global__ __launch_bounds__(512) void gemm_nt3_big(
    const unsigned short* __restrict__ A,
    const unsigned short* __restrict__ Bt,
    float* __restrict__ C,
    const float* __restrict__ addsrc,
    float scale) {
  __shared__ short As[3][128 * BKK];   // 48 KB
  __shared__ short Bs[3][128 * BKK];   // 48 KB
  int b = blockIdx.z;
  int m0 = blockIdx.x * 128, n0 = blockIdx.y * 128;
  int tid = threadIdx.x, lane = tid & 63, wid = tid >> 6;   // wid 0..7
  int wm = wid >> 1, wn = wid & 1;
  f32x4 acc[2][4] = {};

  // stage: lane l -> 16B at linear offset l*16 => local row (l>>3), chunk (l&7);
  // logical chunk stored = (l&7)^(l>>3) => pre-swizzle the global k-offset.
  int sk0 = (((lane & 7) ^ (lane >> 3)) * 8);
  int srow0 = wid * 8 + (lane >> 3);   // 0..63
  int fr = lane & 15;
  int r7 = fr & 7;

  const unsigned short* Ap[3];
  const unsigned short* Bp[3];
#pragma unroll
  for (int p = 0; p < 3; ++p) {
    Ap[p] = A + p * PLANE + b * MS;
    Bp[p] = Bt + p * PLANE + b * MS;
  }

  for (int kt = 0; kt < 1024 / BKK; ++kt) {
    int kbase = kt * BKK;
#pragma unroll
    for (int p = 0; p < 3; ++p) {
#pragma unroll
      for (int r = 0; r < 2; ++r) {
        int row = r * 64 + srow0;
        gld_lds16(Ap[p] + (size_t)(m0 + row) * 1024 + kbase + sk0, &As[p][(r * 64 + wid * 8) * BKK]);
        gld_lds16(Bp[p] + (size_t)(n0 + row) * 1024 + kbase + sk0, &Bs[p][(r * 64 + wid * 8) * BKK]);
      }
    }
    __syncthreads();
#pragma unroll
    for (int kk = 0; kk < 2; ++kk) {
      int fkc = (((kk * 4 + (lane >> 4)) ^ r7) * 8);   // swizzled read chunk
      bf16x8 af[3][2], bfr[3][4];
#pragma unroll
      for (int p = 0; p < 3; ++p) {
        af[p][0] = *(const bf16x8*)&As[p][(wm * 32 + fr) * BKK + fkc];
        af[p][1] = *(const bf16x8*)&As[p][(wm * 32 + 16 + fr) * BKK + fkc];
#pragma unroll
        for (int ni = 0; ni < 4; ++ni)
          bfr[p][ni] = *(const bf16x8*)&Bs[p][(wn * 64 + ni * 16 + fr) * BKK + fkc];
      }
#pragma unroll
      for (int mi = 0; mi < 2; ++mi)
#pragma unroll
        for (int ni = 0; ni < 4; ++ni) {
          acc[mi][ni] = __builtin_amdgcn_mfma_f32_16x16x32_bf16(af[2][mi], bfr[0][ni], acc[mi][ni], 0, 0, 0);
          acc[mi][ni] = __builtin_amdgcn_mfma_f32_16x16x32_bf16(af[1][mi], bfr[1][ni], acc[mi][ni], 0, 0, 0);
          acc[mi][ni] = __builtin_amdgcn_mfma_f32_16x16x32_bf16(af[0][mi], bfr[2][ni], acc[mi][ni], 0, 0, 0);
          acc[mi][ni] = __builtin_amdgcn_mfma_f32_16x16x32_bf16(af[1][mi], bfr[0][ni], acc[mi][ni], 0, 0, 0);
          acc[mi][ni] = __builtin_amdgcn_mfma_f32_16x16x32_bf16(af[0][mi], bfr[1][ni], acc[mi][ni], 0, 0, 0);
          acc[mi][ni] = __builtin_amdgcn_mfma_f32_16x16x32_bf16(af[0][mi], bfr[0][ni], acc[mi][ni], 0, 0, 0);
        }
    }
    __syncthreads();
  }

  float* Cb = C + b * MS;
  const float* Rb = addsrc ? addsrc + b * MS : nullptr;
  int crow0 = (lane >> 4) * 4, ccol = lane & 15;
#pragma unroll
  for (int mi = 0; mi < 2; ++mi)
#pragma unroll
    for (int ni = 0; ni < 4; ++ni) {
      int colg = n0 + wn * 64 + ni * 16 + ccol;
#pragma unroll
      for (int j = 0; j < 4; ++j) {
        int rowg = m0 + wm * 32 + mi * 16 + crow0 + j;
        float vv = acc[mi][ni][j] * scale;
        if (Rb) vv += Rb[(size_t)rowg * 1024 + colg];
        Cb[(size_t)rowg * 1024 + colg] = vv;
      }
    }
}

// ---------------- row softmax -> 3-limb split bf16 ----------------
__global__ __launch_bounds__(256) void softmax_kernel(const float* __restrict__ sc,
                                                      unsigned short* __restrict__ P) {
  int row = blockIdx.x, tid = threadIdx.x;
  int wid = tid >> 6, lane = tid & 63;
  const float4 v = ((const float4*)(sc + (size_t)row * SS))[tid];
  float mx = fmaxf(fmaxf(v.x, v.y), fmaxf(v.z, v.w));
  for (int o = 32; o; o >>= 1) mx = fmaxf(mx, __shfl_down(mx, o));
  __shared__ float red[4];
  __shared__ float bres[2];
  if (lane == 0) red[wid] = mx;
  __syncthreads();
  if (tid == 0) bres[0] = fmaxf(fmaxf(red[0], red[1]), fmaxf(red[2], red[3]));
  __syncthreads();
  float m = bres[0];
  float e0 = expf(v.x - m), e1 = expf(v.y - m), e2 = expf(v.z - m), e3 = expf(v.w - m);
  float s = e0 + e1 + e2 + e3;
  for (int o = 32; o; o >>= 1) s += __shfl_down(s, o);
  if (lane == 0) red[wid] = s;
  __syncthreads();
  if (tid == 0) bres[1] = red[0] + red[1] + red[2] + red[3];
  __syncthreads();
  float inv = 1.f / bres[1];
  float p0 = e0 * inv, p1 = e1 * inv, p2 = e2 * inv, p3 = e3 * inv;
  ushort4 o0, o1, o2;
  split3(p0, o0.x, o1.x, o2.x);
  split3(p1, o0.y, o1.y, o2.y);
  split3(p2, o0.z, o1.z, o2.z);
  split3(p3, o0.w, o1.w, o2.w);
  size_t off = (size_t)row * SS + tid * 4;
  *(ushort4*)(P + off) = o0;
  *(ushort4*)(P + PLANE + off) = o1;
  *(ushort4*)(P + 2 * PLANE + off) = o2;
}

extern "C" void kernel_launch(void* const* d_in, const int* in_sizes, int n_in,
                              void* d_out, int out_size, void* d_ws, size_t ws_size,
                              hipStream_t stream) {
  const float* x = (const float*)d_in[0];
  const float* qp[6]; const float* kp[6]; const float* vp[6]; const float* fp[6];
  for (int i = 0; i < 6; ++i) {
    qp[i] = (const float*)d_in[1 + i];
    kp[i] = (const float*)d_in[7 + i];
    vp[i] = (const float*)d_in[13 + i];
    fp[i] = (const float*)d_in[19 + i];
  }
  char* ws = (char*)d_ws;
  float* xn           = (float*)(ws);                          // [0,8) MB
  unsigned short* qb  = (unsigned short*)(ws + ( 8 << 20));    // [8,20) 3 planes
  unsigned short* kb  = (unsigned short*)(ws + (20 << 20));    // [20,32) 3 planes
  unsigned short* vs  = (unsigned short*)(ws + (32 << 20));    // [32,44) 3 planes
  unsigned short* vt  = (unsigned short*)(ws + (44 << 20));    // [44,56) 3 planes
  float* sc           = (float*)(ws + (32 << 20));             // reuse vs after transpose
  unsigned short* P   = (unsigned short*)(ws + ( 8 << 20));    // reuse qb after gemm1
  float* y            = (float*)(ws + (20 << 20));             // reuse kb after gemm1
  int* meta           = (int*)(ws + (56 << 20));
  int* hist           = meta;                                  // 1024 ints
  int* leaf_arr       = meta + 4096;                           // 8192
  int* list           = meta + 12288;                          // 8192
  int4* desc          = (int4*)(meta + 20480);                 // 4*512 int4
  float* out          = (float*)d_out;

  hipMemsetAsync(hist, 0, 1024 * sizeof(int), stream);
  norm_route_kernel<<<NTOK, 256, 0, stream>>>(x, xn, qp[0], qp[1], kp[0], kp[1], vp[0], vp[1],
                                              leaf_arr, hist);
  scan_scatter_kernel<<<1, 256, 0, stream>>>(hist, leaf_arr, list, desc, 3, 0);

  LeafW Wqkv;
  Wqkv.w1[0] = qp[2]; Wqkv.b1[0] = qp[3]; Wqkv.w2[0] = qp[4]; Wqkv.b2[0] = qp[5];
  Wqkv.w1[1] = kp[2]; Wqkv.b1[1] = kp[3]; Wqkv.w2[1] = kp[4]; Wqkv.b2[1] = kp[5];
  Wqkv.w1[2] = vp[2]; Wqkv.b1[2] = vp[3]; Wqkv.w2[2] = vp[4]; Wqkv.b2[2] = vp[5];
  Wqkv.outs[0] = qb; Wqkv.outs[1] = kb; Wqkv.outs[2] = vs;
  Wqkv.out_res = nullptr;
  leafmlp_kernel<<<dim3(MAXCHUNK, 3), 256, 0, stream>>>(xn, list, desc, Wqkv, 0, 0);

  transpose_v<<<dim3(32, 32, 6), dim3(32, 8), 0, stream>>>(vs, vt);
  gemm_nt3_big<<<dim3(8, 8, 2), 512, 0, stream>>>(qb, kb, sc, nullptr, 0.03125f);
  softmax_kernel<<<NTOK, 256, 0, stream>>>(sc, P);
  gemm_nt3_big<<<dim3(8, 8, 2), 512, 0, stream>>>(P, vt, y, xn, 1.0f);

  route_kernel<<<NTOK / 4, 256, 0, stream>>>(y, fp[0], fp[1], fp[0], fp[1], fp[0], fp[1],
                                             leaf_arr + 3 * NTOK, hist + 3 * NLEAF, 1);
  scan_scatter_kernel<<<1, 256, 0, stream>>>(hist, leaf_arr, list, desc, 1, 3);

  LeafW Wf;
  Wf.w1[0] = fp[2]; Wf.b1[0] = fp[3]; Wf.w2[0] = fp[4]; Wf.b2[0] = fp[5];
  Wf.w1[1] = fp[2]; Wf.b1[1] = fp[3]; Wf.w2[1] = fp[4]; Wf.b2[1] = fp[5];
  Wf.w1[2] = fp[2]; Wf.b1[2] = fp[3]; Wf.w2[2] = fp[4]; Wf.b2[2] = fp[5];
  Wf.outs[0] = nullptr; Wf.outs[1] = nullptr; Wf.outs[2] = nullptr;
  Wf.out_res = out;
  leafmlp_kernel<<<dim3(MAXCHUNK, 1), 256, 0, stream>>>(y, list, desc, Wf, 3, 1);
}

// Round 15
// 183.910 us; speedup vs baseline: 1.2261x; 1.2261x over previous
//
#include <hip/hip_runtime.h>
#include <hip/hip_bf16.h>
#include <math.h>

#define DD 1024
#define LWW 16
#define NNODES 255
#define NLEAF 256
#define BB 2
#define SS 1024
#define NTOK (BB*SS)
#define PLANE ((size_t)NTOK * DD)   // 2M elements per bf16 plane
#define MS ((size_t)1024 * 1024)    // per-batch matrix stride
#define MAXCHUNK 512                // per-tree chunk-descriptor slots
#define CH 8                        // tokens per chunk

typedef short bf16x8 __attribute__((ext_vector_type(8)));
typedef float f32x4 __attribute__((ext_vector_type(4)));

#define GLOBAL_AS __attribute__((address_space(1)))
#define LDS_AS __attribute__((address_space(3)))

__device__ __forceinline__ void gld_lds16(const void* g, void* l) {
  __builtin_amdgcn_global_load_lds((const GLOBAL_AS unsigned int*)g,
                                   (LDS_AS unsigned int*)l, 16, 0, 0);
}

__device__ __forceinline__ unsigned short f2bf(float f) {
  union { float f; unsigned int u; } v; v.f = f;
  unsigned int u = v.u;
  unsigned int lsb = (u >> 16) & 1u;
  u += 0x7fffu + lsb;
  return (unsigned short)(u >> 16);
}
__device__ __forceinline__ float bf2f(unsigned short h) {
  union { unsigned int u; float f; } v; v.u = ((unsigned int)h) << 16;
  return v.f;
}
// split f32 into 3 bf16 limbs (exact to ~2^-24 relative)
__device__ __forceinline__ void split3(float a, unsigned short& h0,
                                       unsigned short& h1, unsigned short& h2) {
  h0 = f2bf(a);
  float r = a - bf2f(h0);
  h1 = f2bf(r);
  float r2 = r - bf2f(h1);
  h2 = f2bf(r2);
}

// ---------------- fused norm + qkv routing ----------------
__global__ __launch_bounds__(256) void norm_route_kernel(
    const float* __restrict__ x, float* __restrict__ xn,
    const float* nw0, const float* nb0,
    const float* nw1, const float* nb1,
    const float* nw2, const float* nb2,
    int* __restrict__ leaf_arr, int* __restrict__ hist) {
  int tok = blockIdx.x, tid = threadIdx.x;
  int wid = tid >> 6, lane = tid & 63;
  __shared__ double rs[4], rs2[4];
  __shared__ float stats[2];
  __shared__ float xs[1024];
  const float4 v = ((const float4*)(x + (size_t)tok * DD))[tid];
  double s = (double)v.x + (double)v.y + (double)v.z + (double)v.w;
  double s2 = (double)v.x * v.x + (double)v.y * v.y + (double)v.z * v.z + (double)v.w * v.w;
  for (int o = 32; o; o >>= 1) { s += __shfl_down(s, o); s2 += __shfl_down(s2, o); }
  if (lane == 0) { rs[wid] = s; rs2[wid] = s2; }
  __syncthreads();
  if (tid == 0) {
    double ts = rs[0] + rs[1] + rs[2] + rs[3];
    double ts2 = rs2[0] + rs2[1] + rs2[2] + rs2[3];
    double mu = ts / DD;
    double var = (ts2 - DD * mu * mu) / (DD - 1);
    if (var < 0) var = 0;
    double sd = sqrt(var);
    stats[0] = (float)mu;
    stats[1] = (float)(1.0 / sqrt(sd + 1e-5));
  }
  __syncthreads();
  float mu = stats[0], inv = stats[1];
  float4 o;
  o.x = (v.x - mu) * inv; o.y = (v.y - mu) * inv;
  o.z = (v.z - mu) * inv; o.w = (v.w - mu) * inv;
  ((float4*)(xn + (size_t)tok * DD))[tid] = o;
  *(float4*)&xs[tid * 4] = o;
  __syncthreads();

  if (wid < 3) {
    const float* nws[3] = {nw0, nw1, nw2};
    const float* nbs[3] = {nb0, nb1, nb2};
    const float* nw = nws[wid];
    const float* nb = nbs[wid];
    f32x4 xq[4];
#pragma unroll
    for (int j = 0; j < 4; ++j) xq[j] = *(const f32x4*)&xs[(lane + 64 * j) * 4];
    int node = 0;
#pragma unroll 1
    for (int step = 0; step < 8; ++step) {
      const f32x4* wb = (const f32x4*)(nw + (size_t)node * DD);
      double p = 0.0;
#pragma unroll
      for (int j = 0; j < 4; ++j) {
        f32x4 w = wb[lane + 64 * j];
        p += (double)xq[j][0] * w[0] + (double)xq[j][1] * w[1] +
             (double)xq[j][2] * w[2] + (double)xq[j][3] * w[3];
      }
#pragma unroll
      for (int o2 = 1; o2 < 64; o2 <<= 1) p += __shfl_xor(p, o2);
      double logit = p + (double)nb[node];
      node = 2 * node + 1 + (logit > 0.0 ? 1 : 0);
    }
    if (lane == 0) {
      int leaf = node - NNODES;
      leaf_arr[(size_t)wid * NTOK + tok] = leaf;
      atomicAdd(&hist[wid * NLEAF + leaf], 1);
    }
  }
}

// ---------------- routing (standalone, used for f tree on y) ----------------
__global__ __launch_bounds__(256) void route_kernel(
    const float* __restrict__ xin,
    const float* nw0, const float* nb0,
    const float* nw1, const float* nb1,
    const float* nw2, const float* nb2,
    int* __restrict__ leaf_arr, int* __restrict__ hist, int ntree) {
  int tid = threadIdx.x, lane = tid & 63, wid = tid >> 6;
  int gw = blockIdx.x * 4 + wid;
  int tok = gw / ntree, tr = gw - tok * ntree;
  if (tok >= NTOK) return;
  const float* nws[3] = {nw0, nw1, nw2};
  const float* nbs[3] = {nb0, nb1, nb2};
  const float* nw = nws[tr];
  const float* nb = nbs[tr];
  f32x4 xq[4];
  const f32x4* xb = (const f32x4*)(xin + (size_t)tok * DD);
#pragma unroll
  for (int j = 0; j < 4; ++j) xq[j] = xb[lane + 64 * j];
  int node = 0;
#pragma unroll 1
  for (int step = 0; step < 8; ++step) {
    const f32x4* wb = (const f32x4*)(nw + (size_t)node * DD);
    double p = 0.0;
#pragma unroll
    for (int j = 0; j < 4; ++j) {
      f32x4 w = wb[lane + 64 * j];
      p += (double)xq[j][0] * w[0] + (double)xq[j][1] * w[1] +
           (double)xq[j][2] * w[2] + (double)xq[j][3] * w[3];
    }
#pragma unroll
    for (int o = 1; o < 64; o <<= 1) p += __shfl_xor(p, o);
    double logit = p + (double)nb[node];
    node = 2 * node + 1 + (logit > 0.0 ? 1 : 0);
  }
  if (lane == 0) {
    int leaf = node - NNODES;
    leaf_arr[(size_t)tr * NTOK + tok] = leaf;
    atomicAdd(&hist[tr * NLEAF + leaf], 1);
  }
}

// ---------------- fused scan + scatter + desc padding (1 block) ----------------
__global__ __launch_bounds__(256) void scan_scatter_kernel(
    const int* __restrict__ hist, const int* __restrict__ leaf_arr,
    int* __restrict__ list, int4* __restrict__ desc,
    int ntree, int tree0) {
  __shared__ int buf[256];
  __shared__ int cur[256];
  __shared__ int dcnt;
  int tid = threadIdx.x;
  for (int tr = 0; tr < ntree; ++tr) {
    int slot = tree0 + tr;
    int v = hist[slot * NLEAF + tid];
    buf[tid] = v;
    if (tid == 0) dcnt = 0;
    __syncthreads();
    int run = v;
    for (int off = 1; off < 256; off <<= 1) {
      int add = (tid >= off) ? buf[tid - off] : 0;
      __syncthreads();
      run += add;
      buf[tid] = run;
      __syncthreads();
    }
    cur[tid] = run - v;
    if (v > 0) {
      int k = (v + CH - 1) / CH;
      int base = atomicAdd(&dcnt, k);
      int lo = run - v;
      for (int j = 0; j < k; ++j) {
        int s = lo + j * CH;
        int e = min(run, s + CH);
        desc[slot * MAXCHUNK + base + j] = make_int4(tid, s, e, 0);
      }
    }
    __syncthreads();
    for (int i = dcnt + tid; i < MAXCHUNK; i += 256)
      desc[slot * MAXCHUNK + i] = make_int4(-1, 0, 0, 0);
    for (int base = 0; base < NTOK; base += 256) {
      int tok = base + tid;
      int leaf = leaf_arr[(size_t)slot * NTOK + tok];
      int pos = atomicAdd(&cur[leaf], 1);
      list[(size_t)slot * NTOK + pos] = tok;
    }
    __syncthreads();
  }
}

// ---------------- leaf MLP v5 (unchanged) ----------------
struct LeafW {
  const float* w1[3]; const float* b1[3]; const float* w2[3]; const float* b2[3];
  unsigned short* outs[3];   // split-plane bases, or null
  float* out_res;            // residual f32 output (used when outs[ty]==null)
};

__global__ __launch_bounds__(256) void leafmlp_kernel(
    const float* __restrict__ xin,
    const int* __restrict__ list, const int4* __restrict__ desc,
    LeafW W, int tree0, int act) {
  int ty = blockIdx.y;
  int slot = tree0 + ty;
  int4 dsc = desc[slot * MAXCHUNK + blockIdx.x];
  int leaf = dsc.x;
  if (leaf < 0) return;
  int lo = dsc.y, hi = dsc.z;
  const int* L = list + (size_t)slot * NTOK;
  const float* W1 = W.w1[ty] + (size_t)leaf * DD * LWW;
  const float* B1 = W.b1[ty] + (size_t)leaf * LWW;
  const float* W2 = W.w2[ty] + (size_t)leaf * LWW * DD;
  const float* B2 = W.b2[ty] + (size_t)leaf * DD;
  unsigned short* osp = W.outs[ty];
  int tid = threadIdx.x;
  int lane = tid & 63, wid = tid >> 6;

  __shared__ float xsl[CH][1024];
  __shared__ float hpart[4][CH][20];
  __shared__ float hs[CH][16];

  float b1c = B1[tid & 15];

  int r = tid >> 2;
  const float* W1p = W1 + (size_t)r * 16 + (tid & 3) * 4;
  f32x4 wreg[16];
#pragma unroll
  for (int p = 0; p < 16; ++p) wreg[p] = *(const f32x4*)(W1p + (size_t)p * 1024);

  int toks[CH];
#pragma unroll
  for (int t = 0; t < CH; ++t) {
    int idx = lo + t;
    toks[t] = (idx < hi) ? L[idx] : -1;
    if (toks[t] >= 0) {
      float4 v = ((const float4*)(xin + (size_t)toks[t] * DD))[tid];
      *(float4*)&xsl[t][tid * 4] = v;
    } else {
      float4 z = {0.f, 0.f, 0.f, 0.f};
      *(float4*)&xsl[t][tid * 4] = z;
    }
  }
  __syncthreads();

  f32x4 part4[CH];
#pragma unroll
  for (int t = 0; t < CH; ++t) part4[t] = (f32x4){0.f, 0.f, 0.f, 0.f};
#pragma unroll
  for (int p = 0; p < 16; ++p) {
#pragma unroll
    for (int t = 0; t < CH; ++t) {
      float xv = xsl[t][p * 64 + r];
      part4[t] += xv * wreg[p];
    }
  }

  const float* W2p = W2 + tid * 4;
  f32x4 w2a[8];
#pragma unroll
  for (int l = 0; l < 8; ++l) w2a[l] = *(const f32x4*)(W2p + (size_t)l * 1024);
  f32x4 b2v = *(const f32x4*)(B2 + tid * 4);

#pragma unroll
  for (int t = 0; t < CH; ++t) {
    f32x4 v = part4[t];
#pragma unroll
    for (int o = 4; o < 64; o <<= 1) {
      v[0] += __shfl_xor(v[0], o);
      v[1] += __shfl_xor(v[1], o);
      v[2] += __shfl_xor(v[2], o);
      v[3] += __shfl_xor(v[3], o);
    }
    if (lane < 4) *(f32x4*)&hpart[wid][t][lane * 4] = v;
  }
  __syncthreads();

  if (tid < 16 * CH) {
    int t = tid >> 4, c = tid & 15;
    float h = b1c + hpart[0][t][c] + hpart[1][t][c] + hpart[2][t][c] + hpart[3][t][c];
    if (act == 0) h = fmaxf(h, 0.f);
    else h = 0.5f * h * (1.f + erff(h * 0.70710678118654752f));
    hs[t][c] = h;
  }
  __syncthreads();

  f32x4 w2b[8];
#pragma unroll
  for (int l = 0; l < 8; ++l) w2b[l] = *(const f32x4*)(W2p + (size_t)(8 + l) * 1024);
  f32x4 acc[CH];
#pragma unroll
  for (int t = 0; t < CH; ++t) acc[t] = b2v;
#pragma unroll
  for (int l = 0; l < 8; ++l) {
#pragma unroll
    for (int t = 0; t < CH; ++t) acc[t] += w2a[l] * hs[t][l];
  }
#pragma unroll
  for (int l = 0; l < 8; ++l) {
#pragma unroll
    for (int t = 0; t < CH; ++t) acc[t] += w2b[l] * hs[t][8 + l];
  }

#pragma unroll
  for (int t = 0; t < CH; ++t) {
    if (toks[t] < 0) break;
    size_t off = (size_t)toks[t] * DD + tid * 4;
    if (osp) {
      ushort4 o0, o1, o2;
      split3(acc[t][0], o0.x, o1.x, o2.x);
      split3(acc[t][1], o0.y, o1.y, o2.y);
      split3(acc[t][2], o0.z, o1.z, o2.z);
      split3(acc[t][3], o0.w, o1.w, o2.w);
      *(ushort4*)(osp + off) = o0;
      *(ushort4*)(osp + PLANE + off) = o1;
      *(ushort4*)(osp + 2 * PLANE + off) = o2;
    } else {
      float4 xr = *(const float4*)&xsl[t][tid * 4];
      float4 o;
      o.x = xr.x + acc[t][0];
      o.y = xr.y + acc[t][1];
      o.z = xr.z + acc[t][2];
      o.w = xr.w + acc[t][3];
      *(float4*)(W.out_res + off) = o;
    }
  }
}

// ---------------- transpose one bf16 plane-set: v (B,S,D) -> vt (B,D,S) ----------------
__global__ __launch_bounds__(256) void transpose_v(const unsigned short* __restrict__ v,
                                                   unsigned short* __restrict__ vt) {
  __shared__ unsigned short t[32][34];
  int b = blockIdx.z & 1, p = blockIdx.z >> 1;
  int s0 = blockIdx.x * 32, d0 = blockIdx.y * 32;
  int tx = threadIdx.x, ty = threadIdx.y;  // 32 x 8
  const unsigned short* vb = v + p * PLANE + (size_t)b * SS * DD;
  unsigned short* vtb = vt + p * PLANE + (size_t)b * DD * SS;
#pragma unroll
  for (int k = 0; k < 4; ++k) {
    int r = ty + 8 * k;
    t[r][tx] = vb[(size_t)(s0 + r) * DD + d0 + tx];
  }
  __syncthreads();
#pragma unroll
  for (int k = 0; k < 4; ++k) {
    int r = ty + 8 * k;
    vtb[(size_t)(d0 + r) * SS + s0 + tx] = t[tx][r];
  }
}

// ---------------- NT GEMM, 3-limb split bf16, 64x64 tile, XOR-swizzled LDS ----
// Round-12 proven structure + T1 XCD-aware block swizzle (512 blocks/z-slice
// pair; 256 per slice; 256%8==0 -> bijective chunked remap, pure speed hint).
#define BKK 64
__global__ __launch_bounds__(256) void gemm_nt3(
    const unsigned short* __restrict__ A,
    const unsigned short* __restrict__ Bt,
    float* __restrict__ C,
    const float* __restrict__ addsrc,
    float scale) {
  __shared__ short As[3][64 * BKK];
  __shared__ short Bs[3][64 * BKK];
  int b = blockIdx.z;
  // XCD swizzle: lin in [0,256) per z-slice; chunk 32 per XCD
  int lin = blockIdx.x + (blockIdx.y << 4);
  int swz = (lin & 7) * 32 + (lin >> 3);
  int m0 = (swz & 15) * 64, n0 = (swz >> 4) * 64;
  int tid = threadIdx.x, lane = tid & 63, wid = tid >> 6;
  int wm = wid >> 1, wn = wid & 1;
  f32x4 acc[2][2] = {};

  int sk0 = (((lane & 7) ^ (lane >> 3)) * 8);
  int srow0 = wid * 8 + (lane >> 3);
  int fr = lane & 15;
  int r7 = fr & 7;

  const unsigned short* Ap[3];
  const unsigned short* Bp[3];
#pragma unroll
  for (int p = 0; p < 3; ++p) {
    Ap[p] = A + p * PLANE + b * MS;
    Bp[p] = Bt + p * PLANE + b * MS;
  }

  for (int kt = 0; kt < 1024 / BKK; ++kt) {
    int kbase = kt * BKK;
#pragma unroll
    for (int p = 0; p < 3; ++p) {
#pragma unroll
      for (int r = 0; r < 2; ++r) {
        int row = r * 32 + srow0;
        gld_lds16(Ap[p] + (size_t)(m0 + row) * 1024 + kbase + sk0, &As[p][(r * 32 + wid * 8) * BKK]);
        gld_lds16(Bp[p] + (size_t)(n0 + row) * 1024 + kbase + sk0, &Bs[p][(r * 32 + wid * 8) * BKK]);
      }
    }
    __syncthreads();
#pragma unroll
    for (int kk = 0; kk < 2; ++kk) {
      int fkc = (((kk * 4 + (lane >> 4)) ^ r7) * 8);
      bf16x8 af[3][2], bfr[3][2];
#pragma unroll
      for (int p = 0; p < 3; ++p) {
        af[p][0]  = *(const bf16x8*)&As[p][(wm * 32 + fr) * BKK + fkc];
        af[p][1]  = *(const bf16x8*)&As[p][(wm * 32 + 16 + fr) * BKK + fkc];
        bfr[p][0] = *(const bf16x8*)&Bs[p][(wn * 32 + fr) * BKK + fkc];
        bfr[p][1] = *(const bf16x8*)&Bs[p][(wn * 32 + 16 + fr) * BKK + fkc];
      }
#pragma unroll
      for (int mi = 0; mi < 2; ++mi)
#pragma unroll
        for (int ni = 0; ni < 2; ++ni) {
          acc[mi][ni] = __builtin_amdgcn_mfma_f32_16x16x32_bf16(af[2][mi], bfr[0][ni], acc[mi][ni], 0, 0, 0);
          acc[mi][ni] = __builtin_amdgcn_mfma_f32_16x16x32_bf16(af[1][mi], bfr[1][ni], acc[mi][ni], 0, 0, 0);
          acc[mi][ni] = __builtin_amdgcn_mfma_f32_16x16x32_bf16(af[0][mi], bfr[2][ni], acc[mi][ni], 0, 0, 0);
          acc[mi][ni] = __builtin_amdgcn_mfma_f32_16x16x32_bf16(af[1][mi], bfr[0][ni], acc[mi][ni], 0, 0, 0);
          acc[mi][ni] = __builtin_amdgcn_mfma_f32_16x16x32_bf16(af[0][mi], bfr[1][ni], acc[mi][ni], 0, 0, 0);
          acc[mi][ni] = __builtin_amdgcn_mfma_f32_16x16x32_bf16(af[0][mi], bfr[0][ni], acc[mi][ni], 0, 0, 0);
        }
    }
    __syncthreads();
  }

  float* Cb = C + b * MS;
  const float* Rb = addsrc ? addsrc + b * MS : nullptr;
  int crow0 = (lane >> 4) * 4, ccol = lane & 15;
#pragma unroll
  for (int mi = 0; mi < 2; ++mi)
#pragma unroll
    for (int ni = 0; ni < 2; ++ni) {
      int colg = n0 + wn * 32 + ni * 16 + ccol;
#pragma unroll
      for (int j = 0; j < 4; ++j) {
        int rowg = m0 + wm * 32 + mi * 16 + crow0 + j;
        float vv = acc[mi][ni][j] * scale;
        if (Rb) vv += Rb[(size_t)rowg * 1024 + colg];
        Cb[(size_t)rowg * 1024 + colg] = vv;
      }
    }
}

// ---------------- row softmax -> 3-limb split bf16 ----------------
__global__ __launch_bounds__(256) void softmax_kernel(const float* __restrict__ sc,
                                                      unsigned short* __restrict__ P) {
  int row = blockIdx.x, tid = threadIdx.x;
  int wid = tid >> 6, lane = tid & 63;
  const float4 v = ((const float4*)(sc + (size_t)row * SS))[tid];
  float mx = fmaxf(fmaxf(v.x, v.y), fmaxf(v.z, v.w));
  for (int o = 32; o; o >>= 1) mx = fmaxf(mx, __shfl_down(mx, o));
  __shared__ float red[4];
  __shared__ float bres[2];
  if (lane == 0) red[wid] = mx;
  __syncthreads();
  if (tid == 0) bres[0] = fmaxf(fmaxf(red[0], red[1]), fmaxf(red[2], red[3]));
  __syncthreads();
  float m = bres[0];
  float e0 = expf(v.x - m), e1 = expf(v.y - m), e2 = expf(v.z - m), e3 = expf(v.w - m);
  float s = e0 + e1 + e2 + e3;
  for (int o = 32; o; o >>= 1) s += __shfl_down(s, o);
  if (lane == 0) red[wid] = s;
  __syncthreads();
  if (tid == 0) bres[1] = red[0] + red[1] + red[2] + red[3];
  __syncthreads();
  float inv = 1.f / bres[1];
  float p0 = e0 * inv, p1 = e1 * inv, p2 = e2 * inv, p3 = e3 * inv;
  ushort4 o0, o1, o2;
  split3(p0, o0.x, o1.x, o2.x);
  split3(p1, o0.y, o1.y, o2.y);
  split3(p2, o0.z, o1.z, o2.z);
  split3(p3, o0.w, o1.w, o2.w);
  size_t off = (size_t)row * SS + tid * 4;
  *(ushort4*)(P + off) = o0;
  *(ushort4*)(P + PLANE + off) = o1;
  *(ushort4*)(P + 2 * PLANE + off) = o2;
}

extern "C" void kernel_launch(void* const* d_in, const int* in_sizes, int n_in,
                              void* d_out, int out_size, void* d_ws, size_t ws_size,
                              hipStream_t stream) {
  const float* x = (const float*)d_in[0];
  const float* qp[6]; const float* kp[6]; const float* vp[6]; const float* fp[6];
  for (int i = 0; i < 6; ++i) {
    qp[i] = (const float*)d_in[1 + i];
    kp[i] = (const float*)d_in[7 + i];
    vp[i] = (const float*)d_in[13 + i];
    fp[i] = (const float*)d_in[19 + i];
  }
  char* ws = (char*)d_ws;
  float* xn           = (float*)(ws);                          // [0,8) MB
  unsigned short* qb  = (unsigned short*)(ws + ( 8 << 20));    // [8,20) 3 planes
  unsigned short* kb  = (unsigned short*)(ws + (20 << 20));    // [20,32) 3 planes
  unsigned short* vs  = (unsigned short*)(ws + (32 << 20));    // [32,44) 3 planes
  unsigned short* vt  = (unsigned short*)(ws + (44 << 20));    // [44,56) 3 planes
  float* sc           = (float*)(ws + (32 << 20));             // reuse vs after transpose
  unsigned short* P   = (unsigned short*)(ws + ( 8 << 20));    // reuse qb after gemm1
  float* y            = (float*)(ws + (20 << 20));             // reuse kb after gemm1
  int* meta           = (int*)(ws + (56 << 20));
  int* hist           = meta;                                  // 1024 ints
  int* leaf_arr       = meta + 4096;                           // 8192
  int* list           = meta + 12288;                          // 8192
  int4* desc          = (int4*)(meta + 20480);                 // 4*512 int4
  float* out          = (float*)d_out;

  hipMemsetAsync(hist, 0, 1024 * sizeof(int), stream);
  norm_route_kernel<<<NTOK, 256, 0, stream>>>(x, xn, qp[0], qp[1], kp[0], kp[1], vp[0], vp[1],
                                              leaf_arr, hist);
  scan_scatter_kernel<<<1, 256, 0, stream>>>(hist, leaf_arr, list, desc, 3, 0);

  LeafW Wqkv;
  Wqkv.w1[0] = qp[2]; Wqkv.b1[0] = qp[3]; Wqkv.w2[0] = qp[4]; Wqkv.b2[0] = qp[5];
  Wqkv.w1[1] = kp[2]; Wqkv.b1[1] = kp[3]; Wqkv.w2[1] = kp[4]; Wqkv.b2[1] = kp[5];
  Wqkv.w1[2] = vp[2]; Wqkv.b1[2] = vp[3]; Wqkv.w2[2] = vp[4]; Wqkv.b2[2] = vp[5];
  Wqkv.outs[0] = qb; Wqkv.outs[1] = kb; Wqkv.outs[2] = vs;
  Wqkv.out_res = nullptr;
  leafmlp_kernel<<<dim3(MAXCHUNK, 3), 256, 0, stream>>>(xn, list, desc, Wqkv, 0, 0);

  transpose_v<<<dim3(32, 32, 6), dim3(32, 8), 0, stream>>>(vs, vt);
  gemm_nt3<<<dim3(16, 16, 2), 256, 0, stream>>>(qb, kb, sc, nullptr, 0.03125f);
  softmax_kernel<<<NTOK, 256, 0, stream>>>(sc, P);
  gemm_nt3<<<dim3(16, 16, 2), 256, 0, stream>>>(P, vt, y, xn, 1.0f);

  route_kernel<<<NTOK / 4, 256, 0, stream>>>(y, fp[0], fp[1], fp[0], fp[1], fp[0], fp[1],
                                             leaf_arr + 3 * NTOK, hist + 3 * NLEAF, 1);
  scan_scatter_kernel<<<1, 256, 0, stream>>>(hist, leaf_arr, list, desc, 1, 3);

  LeafW Wf;
  Wf.w1[0] = fp[2]; Wf.b1[0] = fp[3]; Wf.w2[0] = fp[4]; Wf.b2[0] = fp[5];
  Wf.w1[1] = fp[2]; Wf.b1[1] = fp[3]; Wf.w2[1] = fp[4]; Wf.b2[1] = fp[5];
  Wf.w1[2] = fp[2]; Wf.b1[2] = fp[3]; Wf.w2[2] = fp[4]; Wf.b2[2] = fp[5];
  Wf.outs[0] = nullptr; Wf.outs[1] = nullptr; Wf.outs[2] = nullptr;
  Wf.out_res = out;
  leafmlp_kernel<<<dim3(MAXCHUNK, 1), 256, 0, stream>>>(y, list, desc, Wf, 3, 1);
}

// Round 16
// 181.652 us; speedup vs baseline: 1.2413x; 1.0124x over previous
//
#include <hip/hip_runtime.h>
#include <hip/hip_bf16.h>
#include <math.h>

#define DD 1024
#define LWW 16
#define NNODES 255
#define NLEAF 256
#define BB 2
#define SS 1024
#define NTOK (BB*SS)
#define PLANE ((size_t)NTOK * DD)   // 2M elements per bf16 plane
#define MS ((size_t)1024 * 1024)    // per-batch matrix stride
#define MAXCHUNK 512                // per-tree chunk-descriptor slots
#define CH 8                        // tokens per chunk

typedef short bf16x8 __attribute__((ext_vector_type(8)));
typedef float f32x4 __attribute__((ext_vector_type(4)));

#define GLOBAL_AS __attribute__((address_space(1)))
#define LDS_AS __attribute__((address_space(3)))

__device__ __forceinline__ void gld_lds16(const void* g, void* l) {
  __builtin_amdgcn_global_load_lds((const GLOBAL_AS unsigned int*)g,
                                   (LDS_AS unsigned int*)l, 16, 0, 0);
}

__device__ __forceinline__ unsigned short f2bf(float f) {
  union { float f; unsigned int u; } v; v.f = f;
  unsigned int u = v.u;
  unsigned int lsb = (u >> 16) & 1u;
  u += 0x7fffu + lsb;
  return (unsigned short)(u >> 16);
}
__device__ __forceinline__ float bf2f(unsigned short h) {
  union { unsigned int u; float f; } v; v.u = ((unsigned int)h) << 16;
  return v.f;
}
// split f32 into 3 bf16 limbs (exact to ~2^-24 relative)
__device__ __forceinline__ void split3(float a, unsigned short& h0,
                                       unsigned short& h1, unsigned short& h2) {
  h0 = f2bf(a);
  float r = a - bf2f(h0);
  h1 = f2bf(r);
  float r2 = r - bf2f(h1);
  h2 = f2bf(r2);
}

// ---------------- fused norm + qkv routing ----------------
__global__ __launch_bounds__(256) void norm_route_kernel(
    const float* __restrict__ x, float* __restrict__ xn,
    const float* nw0, const float* nb0,
    const float* nw1, const float* nb1,
    const float* nw2, const float* nb2,
    int* __restrict__ leaf_arr, int* __restrict__ hist) {
  int tok = blockIdx.x, tid = threadIdx.x;
  int wid = tid >> 6, lane = tid & 63;
  __shared__ double rs[4], rs2[4];
  __shared__ float stats[2];
  __shared__ float xs[1024];
  const float4 v = ((const float4*)(x + (size_t)tok * DD))[tid];
  double s = (double)v.x + (double)v.y + (double)v.z + (double)v.w;
  double s2 = (double)v.x * v.x + (double)v.y * v.y + (double)v.z * v.z + (double)v.w * v.w;
  for (int o = 32; o; o >>= 1) { s += __shfl_down(s, o); s2 += __shfl_down(s2, o); }
  if (lane == 0) { rs[wid] = s; rs2[wid] = s2; }
  __syncthreads();
  if (tid == 0) {
    double ts = rs[0] + rs[1] + rs[2] + rs[3];
    double ts2 = rs2[0] + rs2[1] + rs2[2] + rs2[3];
    double mu = ts / DD;
    double var = (ts2 - DD * mu * mu) / (DD - 1);
    if (var < 0) var = 0;
    double sd = sqrt(var);
    stats[0] = (float)mu;
    stats[1] = (float)(1.0 / sqrt(sd + 1e-5));
  }
  __syncthreads();
  float mu = stats[0], inv = stats[1];
  float4 o;
  o.x = (v.x - mu) * inv; o.y = (v.y - mu) * inv;
  o.z = (v.z - mu) * inv; o.w = (v.w - mu) * inv;
  ((float4*)(xn + (size_t)tok * DD))[tid] = o;
  *(float4*)&xs[tid * 4] = o;
  __syncthreads();

  if (wid < 3) {
    const float* nws[3] = {nw0, nw1, nw2};
    const float* nbs[3] = {nb0, nb1, nb2};
    const float* nw = nws[wid];
    const float* nb = nbs[wid];
    f32x4 xq[4];
#pragma unroll
    for (int j = 0; j < 4; ++j) xq[j] = *(const f32x4*)&xs[(lane + 64 * j) * 4];
    int node = 0;
#pragma unroll 1
    for (int step = 0; step < 8; ++step) {
      const f32x4* wb = (const f32x4*)(nw + (size_t)node * DD);
      double p = 0.0;
#pragma unroll
      for (int j = 0; j < 4; ++j) {
        f32x4 w = wb[lane + 64 * j];
        p += (double)xq[j][0] * w[0] + (double)xq[j][1] * w[1] +
             (double)xq[j][2] * w[2] + (double)xq[j][3] * w[3];
      }
#pragma unroll
      for (int o2 = 1; o2 < 64; o2 <<= 1) p += __shfl_xor(p, o2);
      double logit = p + (double)nb[node];
      node = 2 * node + 1 + (logit > 0.0 ? 1 : 0);
    }
    if (lane == 0) {
      int leaf = node - NNODES;
      leaf_arr[(size_t)wid * NTOK + tok] = leaf;
      atomicAdd(&hist[wid * NLEAF + leaf], 1);
    }
  }
}

// ---------------- routing (standalone, used for f tree on y) ----------------
__global__ __launch_bounds__(256) void route_kernel(
    const float* __restrict__ xin,
    const float* nw0, const float* nb0,
    const float* nw1, const float* nb1,
    const float* nw2, const float* nb2,
    int* __restrict__ leaf_arr, int* __restrict__ hist, int ntree) {
  int tid = threadIdx.x, lane = tid & 63, wid = tid >> 6;
  int gw = blockIdx.x * 4 + wid;
  int tok = gw / ntree, tr = gw - tok * ntree;
  if (tok >= NTOK) return;
  const float* nws[3] = {nw0, nw1, nw2};
  const float* nbs[3] = {nb0, nb1, nb2};
  const float* nw = nws[tr];
  const float* nb = nbs[tr];
  f32x4 xq[4];
  const f32x4* xb = (const f32x4*)(xin + (size_t)tok * DD);
#pragma unroll
  for (int j = 0; j < 4; ++j) xq[j] = xb[lane + 64 * j];
  int node = 0;
#pragma unroll 1
  for (int step = 0; step < 8; ++step) {
    const f32x4* wb = (const f32x4*)(nw + (size_t)node * DD);
    double p = 0.0;
#pragma unroll
    for (int j = 0; j < 4; ++j) {
      f32x4 w = wb[lane + 64 * j];
      p += (double)xq[j][0] * w[0] + (double)xq[j][1] * w[1] +
           (double)xq[j][2] * w[2] + (double)xq[j][3] * w[3];
    }
#pragma unroll
    for (int o = 1; o < 64; o <<= 1) p += __shfl_xor(p, o);
    double logit = p + (double)nb[node];
    node = 2 * node + 1 + (logit > 0.0 ? 1 : 0);
  }
  if (lane == 0) {
    int leaf = node - NNODES;
    leaf_arr[(size_t)tr * NTOK + tok] = leaf;
    atomicAdd(&hist[tr * NLEAF + leaf], 1);
  }
}

// ---------------- fused scan + scatter + desc padding (1 block) ----------------
__global__ __launch_bounds__(256) void scan_scatter_kernel(
    const int* __restrict__ hist, const int* __restrict__ leaf_arr,
    int* __restrict__ list, int4* __restrict__ desc,
    int ntree, int tree0) {
  __shared__ int buf[256];
  __shared__ int cur[256];
  __shared__ int dcnt;
  int tid = threadIdx.x;
  for (int tr = 0; tr < ntree; ++tr) {
    int slot = tree0 + tr;
    int v = hist[slot * NLEAF + tid];
    buf[tid] = v;
    if (tid == 0) dcnt = 0;
    __syncthreads();
    int run = v;
    for (int off = 1; off < 256; off <<= 1) {
      int add = (tid >= off) ? buf[tid - off] : 0;
      __syncthreads();
      run += add;
      buf[tid] = run;
      __syncthreads();
    }
    cur[tid] = run - v;
    if (v > 0) {
      int k = (v + CH - 1) / CH;
      int base = atomicAdd(&dcnt, k);
      int lo = run - v;
      for (int j = 0; j < k; ++j) {
        int s = lo + j * CH;
        int e = min(run, s + CH);
        desc[slot * MAXCHUNK + base + j] = make_int4(tid, s, e, 0);
      }
    }
    __syncthreads();
    for (int i = dcnt + tid; i < MAXCHUNK; i += 256)
      desc[slot * MAXCHUNK + i] = make_int4(-1, 0, 0, 0);
    for (int base = 0; base < NTOK; base += 256) {
      int tok = base + tid;
      int leaf = leaf_arr[(size_t)slot * NTOK + tok];
      int pos = atomicAdd(&cur[leaf], 1);
      list[(size_t)slot * NTOK + pos] = tok;
    }
    __syncthreads();
  }
}

// ---------------- leaf MLP v6: gld_lds x-staging + all-upfront w1 registers ----
struct LeafW {
  const float* w1[3]; const float* b1[3]; const float* w2[3]; const float* b2[3];
  unsigned short* outs[3];   // split-plane bases, or null
  float* out_res;            // residual f32 output (used when outs[ty]==null)
};

// v6 vs v5: x rows staged via global_load_lds (wave-uniform base + lane*16,
// linear dest - the m104-compatible pattern), ISSUED BEFORE the w1 register
// loads so both streams are in flight; one __syncthreads drains all (compiler
// emits the vmcnt). Removes 8 float4 VGPR round-trips + 8 ds_writes from the
// pre-barrier chain. Padded slots stage row L[lo] (finite, epilogue-skipped).
__global__ __launch_bounds__(256) void leafmlp_kernel(
    const float* __restrict__ xin,
    const int* __restrict__ list, const int4* __restrict__ desc,
    LeafW W, int tree0, int act) {
  int ty = blockIdx.y;
  int slot = tree0 + ty;
  int4 dsc = desc[slot * MAXCHUNK + blockIdx.x];
  int leaf = dsc.x;
  if (leaf < 0) return;
  int lo = dsc.y, hi = dsc.z;
  const int* L = list + (size_t)slot * NTOK;
  const float* W1 = W.w1[ty] + (size_t)leaf * DD * LWW;
  const float* B1 = W.b1[ty] + (size_t)leaf * LWW;
  const float* W2 = W.w2[ty] + (size_t)leaf * LWW * DD;
  const float* B2 = W.b2[ty] + (size_t)leaf * DD;
  unsigned short* osp = W.outs[ty];
  int tid = threadIdx.x;
  int lane = tid & 63, wid = tid >> 6;

  __shared__ float xsl[CH][1024];
  __shared__ float hpart[4][CH][20];
  __shared__ float hs[CH][16];

  // token indices (scalar loads; small)
  int toks[CH];
#pragma unroll
  for (int t = 0; t < CH; ++t) {
    int idx = lo + t;
    int v = (idx < hi) ? L[idx] : -1;
    toks[t] = v;
  }
  int padtok = L[lo];

  // stage x rows via async global->LDS (8 calls/wave, linear dest)
#pragma unroll
  for (int t = 0; t < CH; ++t) {
    int srctok = (toks[t] >= 0) ? toks[t] : padtok;
    gld_lds16(xin + (size_t)srctok * DD + wid * 256 + lane * 4, &xsl[t][wid * 256]);
  }

  float b1c = B1[tid & 15];

  // w1 register prefetch (16 independent f32x4 loads in flight)
  int r = tid >> 2;
  const float* W1p = W1 + (size_t)r * 16 + (tid & 3) * 4;
  f32x4 wreg[16];
#pragma unroll
  for (int p = 0; p < 16; ++p) wreg[p] = *(const f32x4*)(W1p + (size_t)p * 1024);

  __syncthreads();   // drains gld_lds (vmcnt) + makes xsl visible

  f32x4 part4[CH];
#pragma unroll
  for (int t = 0; t < CH; ++t) part4[t] = (f32x4){0.f, 0.f, 0.f, 0.f};
#pragma unroll
  for (int p = 0; p < 16; ++p) {
#pragma unroll
    for (int t = 0; t < CH; ++t) {
      float xv = xsl[t][p * 64 + r];
      part4[t] += xv * wreg[p];
    }
  }

  const float* W2p = W2 + tid * 4;
  f32x4 w2a[8];
#pragma unroll
  for (int l = 0; l < 8; ++l) w2a[l] = *(const f32x4*)(W2p + (size_t)l * 1024);
  f32x4 b2v = *(const f32x4*)(B2 + tid * 4);

#pragma unroll
  for (int t = 0; t < CH; ++t) {
    f32x4 v = part4[t];
#pragma unroll
    for (int o = 4; o < 64; o <<= 1) {
      v[0] += __shfl_xor(v[0], o);
      v[1] += __shfl_xor(v[1], o);
      v[2] += __shfl_xor(v[2], o);
      v[3] += __shfl_xor(v[3], o);
    }
    if (lane < 4) *(f32x4*)&hpart[wid][t][lane * 4] = v;
  }
  __syncthreads();

  if (tid < 16 * CH) {
    int t = tid >> 4, c = tid & 15;
    float h = b1c + hpart[0][t][c] + hpart[1][t][c] + hpart[2][t][c] + hpart[3][t][c];
    if (act == 0) h = fmaxf(h, 0.f);
    else h = 0.5f * h * (1.f + erff(h * 0.70710678118654752f));
    hs[t][c] = h;
  }
  __syncthreads();

  f32x4 w2b[8];
#pragma unroll
  for (int l = 0; l < 8; ++l) w2b[l] = *(const f32x4*)(W2p + (size_t)(8 + l) * 1024);
  f32x4 acc[CH];
#pragma unroll
  for (int t = 0; t < CH; ++t) acc[t] = b2v;
#pragma unroll
  for (int l = 0; l < 8; ++l) {
#pragma unroll
    for (int t = 0; t < CH; ++t) acc[t] += w2a[l] * hs[t][l];
  }
#pragma unroll
  for (int l = 0; l < 8; ++l) {
#pragma unroll
    for (int t = 0; t < CH; ++t) acc[t] += w2b[l] * hs[t][8 + l];
  }

#pragma unroll
  for (int t = 0; t < CH; ++t) {
    if (toks[t] < 0) break;
    size_t off = (size_t)toks[t] * DD + tid * 4;
    if (osp) {
      ushort4 o0, o1, o2;
      split3(acc[t][0], o0.x, o1.x, o2.x);
      split3(acc[t][1], o0.y, o1.y, o2.y);
      split3(acc[t][2], o0.z, o1.z, o2.z);
      split3(acc[t][3], o0.w, o1.w, o2.w);
      *(ushort4*)(osp + off) = o0;
      *(ushort4*)(osp + PLANE + off) = o1;
      *(ushort4*)(osp + 2 * PLANE + off) = o2;
    } else {
      float4 xr = *(const float4*)&xsl[t][tid * 4];
      float4 o;
      o.x = xr.x + acc[t][0];
      o.y = xr.y + acc[t][1];
      o.z = xr.z + acc[t][2];
      o.w = xr.w + acc[t][3];
      *(float4*)(W.out_res + off) = o;
    }
  }
}

// ---------------- transpose one bf16 plane-set: v (B,S,D) -> vt (B,D,S) ----------------
__global__ __launch_bounds__(256) void transpose_v(const unsigned short* __restrict__ v,
                                                   unsigned short* __restrict__ vt) {
  __shared__ unsigned short t[32][34];
  int b = blockIdx.z & 1, p = blockIdx.z >> 1;
  int s0 = blockIdx.x * 32, d0 = blockIdx.y * 32;
  int tx = threadIdx.x, ty = threadIdx.y;  // 32 x 8
  const unsigned short* vb = v + p * PLANE + (size_t)b * SS * DD;
  unsigned short* vtb = vt + p * PLANE + (size_t)b * DD * SS;
#pragma unroll
  for (int k = 0; k < 4; ++k) {
    int r = ty + 8 * k;
    t[r][tx] = vb[(size_t)(s0 + r) * DD + d0 + tx];
  }
  __syncthreads();
#pragma unroll
  for (int k = 0; k < 4; ++k) {
    int r = ty + 8 * k;
    vtb[(size_t)(d0 + r) * SS + s0 + tx] = t[tx][r];
  }
}

// ---------------- NT GEMM, 3-limb split bf16, 64x64 tile, XOR-swizzled LDS ----
// T1 XCD-aware swizzle (256 blocks/z-slice, 256%8==0 -> bijective).
#define BKK 64
__global__ __launch_bounds__(256) void gemm_nt3(
    const unsigned short* __restrict__ A,
    const unsigned short* __restrict__ Bt,
    float* __restrict__ C,
    const float* __restrict__ addsrc,
    float scale) {
  __shared__ short As[3][64 * BKK];
  __shared__ short Bs[3][64 * BKK];
  int b = blockIdx.z;
  int lin = blockIdx.x + (blockIdx.y << 4);
  int swz = (lin & 7) * 32 + (lin >> 3);
  int m0 = (swz & 15) * 64, n0 = (swz >> 4) * 64;
  int tid = threadIdx.x, lane = tid & 63, wid = tid >> 6;
  int wm = wid >> 1, wn = wid & 1;
  f32x4 acc[2][2] = {};

  int sk0 = (((lane & 7) ^ (lane >> 3)) * 8);
  int srow0 = wid * 8 + (lane >> 3);
  int fr = lane & 15;
  int r7 = fr & 7;

  const unsigned short* Ap[3];
  const unsigned short* Bp[3];
#pragma unroll
  for (int p = 0; p < 3; ++p) {
    Ap[p] = A + p * PLANE + b * MS;
    Bp[p] = Bt + p * PLANE + b * MS;
  }

  for (int kt = 0; kt < 1024 / BKK; ++kt) {
    int kbase = kt * BKK;
#pragma unroll
    for (int p = 0; p < 3; ++p) {
#pragma unroll
      for (int r = 0; r < 2; ++r) {
        int row = r * 32 + srow0;
        gld_lds16(Ap[p] + (size_t)(m0 + row) * 1024 + kbase + sk0, &As[p][(r * 32 + wid * 8) * BKK]);
        gld_lds16(Bp[p] + (size_t)(n0 + row) * 1024 + kbase + sk0, &Bs[p][(r * 32 + wid * 8) * BKK]);
      }
    }
    __syncthreads();
#pragma unroll
    for (int kk = 0; kk < 2; ++kk) {
      int fkc = (((kk * 4 + (lane >> 4)) ^ r7) * 8);
      bf16x8 af[3][2], bfr[3][2];
#pragma unroll
      for (int p = 0; p < 3; ++p) {
        af[p][0]  = *(const bf16x8*)&As[p][(wm * 32 + fr) * BKK + fkc];
        af[p][1]  = *(const bf16x8*)&As[p][(wm * 32 + 16 + fr) * BKK + fkc];
        bfr[p][0] = *(const bf16x8*)&Bs[p][(wn * 32 + fr) * BKK + fkc];
        bfr[p][1] = *(const bf16x8*)&Bs[p][(wn * 32 + 16 + fr) * BKK + fkc];
      }
#pragma unroll
      for (int mi = 0; mi < 2; ++mi)
#pragma unroll
        for (int ni = 0; ni < 2; ++ni) {
          acc[mi][ni] = __builtin_amdgcn_mfma_f32_16x16x32_bf16(af[2][mi], bfr[0][ni], acc[mi][ni], 0, 0, 0);
          acc[mi][ni] = __builtin_amdgcn_mfma_f32_16x16x32_bf16(af[1][mi], bfr[1][ni], acc[mi][ni], 0, 0, 0);
          acc[mi][ni] = __builtin_amdgcn_mfma_f32_16x16x32_bf16(af[0][mi], bfr[2][ni], acc[mi][ni], 0, 0, 0);
          acc[mi][ni] = __builtin_amdgcn_mfma_f32_16x16x32_bf16(af[1][mi], bfr[0][ni], acc[mi][ni], 0, 0, 0);
          acc[mi][ni] = __builtin_amdgcn_mfma_f32_16x16x32_bf16(af[0][mi], bfr[1][ni], acc[mi][ni], 0, 0, 0);
          acc[mi][ni] = __builtin_amdgcn_mfma_f32_16x16x32_bf16(af[0][mi], bfr[0][ni], acc[mi][ni], 0, 0, 0);
        }
    }
    __syncthreads();
  }

  float* Cb = C + b * MS;
  const float* Rb = addsrc ? addsrc + b * MS : nullptr;
  int crow0 = (lane >> 4) * 4, ccol = lane & 15;
#pragma unroll
  for (int mi = 0; mi < 2; ++mi)
#pragma unroll
    for (int ni = 0; ni < 2; ++ni) {
      int colg = n0 + wn * 32 + ni * 16 + ccol;
#pragma unroll
      for (int j = 0; j < 4; ++j) {
        int rowg = m0 + wm * 32 + mi * 16 + crow0 + j;
        float vv = acc[mi][ni][j] * scale;
        if (Rb) vv += Rb[(size_t)rowg * 1024 + colg];
        Cb[(size_t)rowg * 1024 + colg] = vv;
      }
    }
}

// ---------------- row softmax -> 3-limb split bf16 ----------------
__global__ __launch_bounds__(256) void softmax_kernel(const float* __restrict__ sc,
                                                      unsigned short* __restrict__ P) {
  int row = blockIdx.x, tid = threadIdx.x;
  int wid = tid >> 6, lane = tid & 63;
  const float4 v = ((const float4*)(sc + (size_t)row * SS))[tid];
  float mx = fmaxf(fmaxf(v.x, v.y), fmaxf(v.z, v.w));
  for (int o = 32; o; o >>= 1) mx = fmaxf(mx, __shfl_down(mx, o));
  __shared__ float red[4];
  __shared__ float bres[2];
  if (lane == 0) red[wid] = mx;
  __syncthreads();
  if (tid == 0) bres[0] = fmaxf(fmaxf(red[0], red[1]), fmaxf(red[2], red[3]));
  __syncthreads();
  float m = bres[0];
  float e0 = expf(v.x - m), e1 = expf(v.y - m), e2 = expf(v.z - m), e3 = expf(v.w - m);
  float s = e0 + e1 + e2 + e3;
  for (int o = 32; o; o >>= 1) s += __shfl_down(s, o);
  if (lane == 0) red[wid] = s;
  __syncthreads();
  if (tid == 0) bres[1] = red[0] + red[1] + red[2] + red[3];
  __syncthreads();
  float inv = 1.f / bres[1];
  float p0 = e0 * inv, p1 = e1 * inv, p2 = e2 * inv, p3 = e3 * inv;
  ushort4 o0, o1, o2;
  split3(p0, o0.x, o1.x, o2.x);
  split3(p1, o0.y, o1.y, o2.y);
  split3(p2, o0.z, o1.z, o2.z);
  split3(p3, o0.w, o1.w, o2.w);
  size_t off = (size_t)row * SS + tid * 4;
  *(ushort4*)(P + off) = o0;
  *(ushort4*)(P + PLANE + off) = o1;
  *(ushort4*)(P + 2 * PLANE + off) = o2;
}

extern "C" void kernel_launch(void* const* d_in, const int* in_sizes, int n_in,
                              void* d_out, int out_size, void* d_ws, size_t ws_size,
                              hipStream_t stream) {
  const float* x = (const float*)d_in[0];
  const float* qp[6]; const float* kp[6]; const float* vp[6]; const float* fp[6];
  for (int i = 0; i < 6; ++i) {
    qp[i] = (const float*)d_in[1 + i];
    kp[i] = (const float*)d_in[7 + i];
    vp[i] = (const float*)d_in[13 + i];
    fp[i] = (const float*)d_in[19 + i];
  }
  char* ws = (char*)d_ws;
  float* xn           = (float*)(ws);                          // [0,8) MB
  unsigned short* qb  = (unsigned short*)(ws + ( 8 << 20));    // [8,20) 3 planes
  unsigned short* kb  = (unsigned short*)(ws + (20 << 20));    // [20,32) 3 planes
  unsigned short* vs  = (unsigned short*)(ws + (32 << 20));    // [32,44) 3 planes
  unsigned short* vt  = (unsigned short*)(ws + (44 << 20));    // [44,56) 3 planes
  float* sc           = (float*)(ws + (32 << 20));             // reuse vs after transpose
  unsigned short* P   = (unsigned short*)(ws + ( 8 << 20));    // reuse qb after gemm1
  float* y            = (float*)(ws + (20 << 20));             // reuse kb after gemm1
  int* meta           = (int*)(ws + (56 << 20));
  int* hist           = meta;                                  // 1024 ints
  int* leaf_arr       = meta + 4096;                           // 8192
  int* list           = meta + 12288;                          // 8192
  int4* desc          = (int4*)(meta + 20480);                 // 4*512 int4
  float* out          = (float*)d_out;

  hipMemsetAsync(hist, 0, 1024 * sizeof(int), stream);
  norm_route_kernel<<<NTOK, 256, 0, stream>>>(x, xn, qp[0], qp[1], kp[0], kp[1], vp[0], vp[1],
                                              leaf_arr, hist);
  scan_scatter_kernel<<<1, 256, 0, stream>>>(hist, leaf_arr, list, desc, 3, 0);

  LeafW Wqkv;
  Wqkv.w1[0] = qp[2]; Wqkv.b1[0] = qp[3]; Wqkv.w2[0] = qp[4]; Wqkv.b2[0] = qp[5];
  Wqkv.w1[1] = kp[2]; Wqkv.b1[1] = kp[3]; Wqkv.w2[1] = kp[4]; Wqkv.b2[1] = kp[5];
  Wqkv.w1[2] = vp[2]; Wqkv.b1[2] = vp[3]; Wqkv.w2[2] = vp[4]; Wqkv.b2[2] = vp[5];
  Wqkv.outs[0] = qb; Wqkv.outs[1] = kb; Wqkv.outs[2] = vs;
  Wqkv.out_res = nullptr;
  leafmlp_kernel<<<dim3(MAXCHUNK, 3), 256, 0, stream>>>(xn, list, desc, Wqkv, 0, 0);

  transpose_v<<<dim3(32, 32, 6), dim3(32, 8), 0, stream>>>(vs, vt);
  gemm_nt3<<<dim3(16, 16, 2), 256, 0, stream>>>(qb, kb, sc, nullptr, 0.03125f);
  softmax_kernel<<<NTOK, 256, 0, stream>>>(sc, P);
  gemm_nt3<<<dim3(16, 16, 2), 256, 0, stream>>>(P, vt, y, xn, 1.0f);

  route_kernel<<<NTOK / 4, 256, 0, stream>>>(y, fp[0], fp[1], fp[0], fp[1], fp[0], fp[1],
                                             leaf_arr + 3 * NTOK, hist + 3 * NLEAF, 1);
  scan_scatter_kernel<<<1, 256, 0, stream>>>(hist, leaf_arr, list, desc, 1, 3);

  LeafW Wf;
  Wf.w1[0] = fp[2]; Wf.b1[0] = fp[3]; Wf.w2[0] = fp[4]; Wf.b2[0] = fp[5];
  Wf.w1[1] = fp[2]; Wf.b1[1] = fp[3]; Wf.w2[1] = fp[4]; Wf.b2[1] = fp[5];
  Wf.w1[2] = fp[2]; Wf.b1[2] = fp[3]; Wf.w2[2] = fp[4]; Wf.b2[2] = fp[5];
  Wf.outs[0] = nullptr; Wf.outs[1] = nullptr; Wf.outs[2] = nullptr;
  Wf.out_res = out;
  leafmlp_kernel<<<dim3(MAXCHUNK, 1), 256, 0, stream>>>(y, list, desc, Wf, 3, 1);
}